// Round 6
// baseline (386.565 us; speedup 1.0000x reference)
//
#include <hip/hip_runtime.h>

// Shift_DWConv: depthwise 3x3 conv with power-of-two (DeepShift) weights.
// x: [B=16, N=4096, C=768] f32 channels-last; out same.
// R4 result: 1-col blocks -> FETCH 355 MB (1.77x), 3.9 TB/s, 145 us.
// R5: per-thread 2D register tile (TW=4 cols x TH=16 rolling rows) cuts
// L2-level read amplification 3.75x -> 1.69x; halo reuse is in-register.

#define DIM 768
#define HD  64
#define WD  64
#define BD  16
#define TW  4          // output columns per thread (w-tile)
#define TH  16         // output rows per block (rolling-register h-sweep)
#define NPIX (HD * WD)

typedef float f32x4 __attribute__((ext_vector_type(4)));

__device__ __forceinline__ float qfix(float x) {
    // round_to_fixed: floor(x * 2^16) * 2^-16, clipped to [-2^15, 2^15 - 1]
    float v = floorf(x * 65536.0f) * 1.52587890625e-05f;
    return fminf(fmaxf(v, -32768.0f), 32767.0f);
}

__device__ __forceinline__ float4 zero4() { return make_float4(0.f, 0.f, 0.f, 0.f); }

__device__ __forceinline__ float4 q4(float4 v) {
    v.x = qfix(v.x); v.y = qfix(v.y); v.z = qfix(v.z); v.w = qfix(v.w);
    return v;
}

__device__ __forceinline__ float4 fma4(float4 a, float4 b, float4 c) {
    c.x = fmaf(a.x, b.x, c.x);
    c.y = fmaf(a.y, b.y, c.y);
    c.z = fmaf(a.z, b.z, c.z);
    c.w = fmaf(a.w, b.w, c.w);
    return c;
}

// Pre-kernel: dequantize power-of-two weights once into ws as [9][768]
// (tap-major so the main kernel's per-tap float4 loads coalesce), and
// fixed-point-quantize bias.
__global__ void wprep_kernel(const float* __restrict__ shift,
                             const float* __restrict__ sgn,
                             const float* __restrict__ bias,
                             float* __restrict__ wbuf,
                             float* __restrict__ bbuf) {
    int i = blockIdx.x * 256 + threadIdx.x;
    if (i < DIM * 9) {
        int c = i / 9;
        int k = i - c * 9;                       // input layout [C][3][3]
        float sr = rintf(fminf(fmaxf(shift[i], -14.0f), 0.0f)); // round(clip(shift))
        float g  = rintf(sgn[i]);                // round(sign_param)
        float sg = (g > 0.0f) ? 1.0f : ((g < 0.0f) ? -1.0f : 0.0f); // sign()
        wbuf[k * DIM + c] = exp2f(sr) * sg;      // 2^shift_r * sign_r
    }
    if (i < DIM) bbuf[i] = qfix(bias[i]);
}

// Load one input row's 6 columns (w0-1 .. w0+4) for this thread's 4 channels.
// All indices compile-time (full unroll) so the array stays in registers.
__device__ __forceinline__ void load_row6(float4* r, const float* p,
                                          bool rowvalid, bool lv, bool rv) {
    #pragma unroll
    for (int j = 0; j < 6; ++j) {
        bool v = rowvalid && (j == 0 ? lv : (j == 5 ? rv : true));
        r[j] = v ? q4(*(const float4*)(p + (j - 1) * DIM)) : zero4();
    }
}

// One block = (batch, 4-col w-tile, 16-row h-strip); 192 threads x float4 = 768 ch.
// Each thread computes TW=4 outputs/row; w-halo reused in-register.
// Rolling registers along h: per output row only 6 new float4 loads for 4 outputs.
__global__ __launch_bounds__(192) void dwconv_kernel(
        const float* __restrict__ x,
        const float* __restrict__ wbuf,
        const float* __restrict__ bbuf,
        float* __restrict__ out) {
    const int c  = threadIdx.x * 4;
    const int w0 = blockIdx.x * TW;
    const int h0 = blockIdx.y * TH;
    const int b  = blockIdx.z;

    float4 wk[9];
    #pragma unroll
    for (int k = 0; k < 9; ++k)
        wk[k] = *(const float4*)(wbuf + k * DIM + c);
    const float4 bq = *(const float4*)(bbuf + c);

    const bool lv = (w0 > 0), rv = (w0 + TW < WD);
    const float* xb = x   + ((size_t)b * NPIX + w0) * DIM + c;  // pixel (h=0, w0)
    float*       ob = out + ((size_t)b * NPIX + w0) * DIM + c;
    const long rowstride = (long)WD * DIM;

    float4 r0[6], r1[6], r2[6];
    load_row6(r0, xb + (long)(h0 - 1) * rowstride, h0 > 0, lv, rv);
    load_row6(r1, xb + (long)h0 * rowstride, true, lv, rv);

    #pragma unroll
    for (int hh = 0; hh < TH; ++hh) {
        const int h = h0 + hh;
        load_row6(r2, xb + (long)(h + 1) * rowstride, (h + 1) < HD, lv, rv);

        float4 acc[TW];
        #pragma unroll
        for (int i = 0; i < TW; ++i) acc[i] = bq;

        // XLA conv = cross-correlation: tap k=ky*3+kx hits row h-1+ky, col w-1+kx.
        // Output col i uses window cols i, i+1, i+2.
        #pragma unroll
        for (int kx = 0; kx < 3; ++kx) {
            #pragma unroll
            for (int i = 0; i < TW; ++i) {
                acc[i] = fma4(wk[0 + kx], r0[i + kx], acc[i]);
                acc[i] = fma4(wk[3 + kx], r1[i + kx], acc[i]);
                acc[i] = fma4(wk[6 + kx], r2[i + kx], acc[i]);
            }
        }

        // Write-once output: nontemporal store keeps the 201 MB write stream
        // from evicting input halo lines neighbor blocks re-read via LLC.
        #pragma unroll
        for (int i = 0; i < TW; ++i) {
            f32x4 av;
            av.x = acc[i].x; av.y = acc[i].y; av.z = acc[i].z; av.w = acc[i].w;
            __builtin_nontemporal_store(av,
                (f32x4*)(ob + (long)h * rowstride + (long)i * DIM));
        }

        #pragma unroll
        for (int j = 0; j < 6; ++j) { r0[j] = r1[j]; r1[j] = r2[j]; }
    }
}

extern "C" void kernel_launch(void* const* d_in, const int* in_sizes, int n_in,
                              void* d_out, int out_size, void* d_ws, size_t ws_size,
                              hipStream_t stream) {
    const float* x     = (const float*)d_in[0];
    const float* shift = (const float*)d_in[1];
    const float* sgn   = (const float*)d_in[2];
    const float* bias  = (const float*)d_in[3];
    float* out  = (float*)d_out;
    float* wbuf = (float*)d_ws;        // 9*768 floats
    float* bbuf = wbuf + 9 * DIM;      // 768 floats  (total 30 KB < ws_size)

    wprep_kernel<<<(DIM * 9 + 255) / 256, 256, 0, stream>>>(shift, sgn, bias, wbuf, bbuf);

    dim3 grid(WD / TW, HD / TH, BD);   // 16 x 4 x 16 = 1024 blocks
    dwconv_kernel<<<grid, 192, 0, stream>>>(x, wbuf, bbuf, out);
}

// Round 7
// 364.361 us; speedup vs baseline: 1.0609x; 1.0609x over previous
//
#include <hip/hip_runtime.h>

// Shift_DWConv: depthwise 3x3 conv with power-of-two (DeepShift) weights.
// x: [B=16, N=4096, C=768] f32 channels-last; out same.
// R4: 1-col blocks, 8192 blk -> FETCH 355MB, 3.9 TB/s, 145 us (fetch-bound).
// R6: TW=4,TH=16, 1024 blk  -> FETCH 158MB, 2.4 TB/s, 152 us (LATENCY-bound:
//     zero prefetch slack, 4 blk/CU, VALUBusy 10%).
// R7: TH=8 (2048 blk) + 4-deep row ring (load h+2 while computing h) + XCD
//     chunk swizzle. Keep TW=4 halo-in-register (L2 amp 1.875x).

#define DIM 768
#define HD  64
#define WD  64
#define BD  16
#define TW  4          // output columns per thread (w-tile)
#define TH  8          // output rows per block (rolling-register h-sweep)
#define NPIX (HD * WD)
#define NBX (WD / TW)  // 16
#define NBY (HD / TH)  // 8
#define NBLK (NBX * NBY * BD)  // 2048, divisible by 8 XCDs

typedef float f32x4 __attribute__((ext_vector_type(4)));

__device__ __forceinline__ float qfix(float x) {
    // round_to_fixed: floor(x * 2^16) * 2^-16, clipped to [-2^15, 2^15 - 1]
    float v = floorf(x * 65536.0f) * 1.52587890625e-05f;
    return fminf(fmaxf(v, -32768.0f), 32767.0f);
}

__device__ __forceinline__ float4 zero4() { return make_float4(0.f, 0.f, 0.f, 0.f); }

__device__ __forceinline__ float4 q4(float4 v) {
    v.x = qfix(v.x); v.y = qfix(v.y); v.z = qfix(v.z); v.w = qfix(v.w);
    return v;
}

__device__ __forceinline__ float4 fma4(float4 a, float4 b, float4 c) {
    c.x = fmaf(a.x, b.x, c.x);
    c.y = fmaf(a.y, b.y, c.y);
    c.z = fmaf(a.z, b.z, c.z);
    c.w = fmaf(a.w, b.w, c.w);
    return c;
}

// Pre-kernel: dequantize power-of-two weights once into ws as [9][768]
// (tap-major so the main kernel's per-tap float4 loads coalesce), and
// fixed-point-quantize bias.
__global__ void wprep_kernel(const float* __restrict__ shift,
                             const float* __restrict__ sgn,
                             const float* __restrict__ bias,
                             float* __restrict__ wbuf,
                             float* __restrict__ bbuf) {
    int i = blockIdx.x * 256 + threadIdx.x;
    if (i < DIM * 9) {
        int c = i / 9;
        int k = i - c * 9;                       // input layout [C][3][3]
        float sr = rintf(fminf(fmaxf(shift[i], -14.0f), 0.0f)); // round(clip(shift))
        float g  = rintf(sgn[i]);                // round(sign_param)
        float sg = (g > 0.0f) ? 1.0f : ((g < 0.0f) ? -1.0f : 0.0f); // sign()
        wbuf[k * DIM + c] = exp2f(sr) * sg;      // 2^shift_r * sign_r
    }
    if (i < DIM) bbuf[i] = qfix(bias[i]);
}

// Load one input row's 6 columns (w0-1 .. w0+4) for this thread's 4 channels.
// All indices compile-time (full unroll) so the array stays in registers.
__device__ __forceinline__ void load_row6(float4* r, const float* p,
                                          bool rowvalid, bool lv, bool rv) {
    #pragma unroll
    for (int j = 0; j < 6; ++j) {
        bool v = rowvalid && (j == 0 ? lv : (j == 5 ? rv : true));
        r[j] = v ? q4(*(const float4*)(p + (j - 1) * DIM)) : zero4();
    }
}

// One block = (batch, 4-col w-tile, 8-row h-strip); 192 threads x float4 = 768 ch.
// 4-deep row ring: iteration hh ISSUES loads for row h+2 (buffer D) while
// COMPUTING row h from A,B,C -> one full compute body of load-latency slack.
__global__ __launch_bounds__(192) void dwconv_kernel(
        const float* __restrict__ x,
        const float* __restrict__ wbuf,
        const float* __restrict__ bbuf,
        float* __restrict__ out) {
    // Bijective XCD-chunk swizzle: each XCD owns a contiguous 1/8 of the grid
    // so w/h-neighbor blocks (which share halo lines) hit the same XCD L2.
    int nbid = blockIdx.x + NBX * (blockIdx.y + NBY * blockIdx.z);
    int swz  = (nbid & 7) * (NBLK / 8) + (nbid >> 3);
    const int bx = swz % NBX; swz /= NBX;
    const int by = swz % NBY; swz /= NBY;
    const int bz = swz;

    const int c  = threadIdx.x * 4;
    const int w0 = bx * TW;
    const int h0 = by * TH;
    const int b  = bz;

    float4 wk[9];
    #pragma unroll
    for (int k = 0; k < 9; ++k)
        wk[k] = *(const float4*)(wbuf + k * DIM + c);
    const float4 bq = *(const float4*)(bbuf + c);

    const bool lv = (w0 > 0), rv = (w0 + TW < WD);
    const float* xb = x   + ((size_t)b * NPIX + w0) * DIM + c;  // pixel (h=0, w0)
    float*       ob = out + ((size_t)b * NPIX + w0) * DIM + c;
    const long rowstride = (long)WD * DIM;

    float4 A[6], B[6], C[6], D[6];
    load_row6(A, xb + (long)(h0 - 1) * rowstride, h0 > 0, lv, rv);
    load_row6(B, xb + (long)h0 * rowstride, true, lv, rv);
    load_row6(C, xb + (long)(h0 + 1) * rowstride, (h0 + 1) < HD, lv, rv);

    #pragma unroll
    for (int hh = 0; hh < TH; ++hh) {
        const int h = h0 + hh;
        // Prefetch row h+2 for NEXT iteration (skip on last iter: unused).
        if (hh < TH - 1)
            load_row6(D, xb + (long)(h + 2) * rowstride, (h + 2) < HD, lv, rv);

        float4 acc[TW];
        #pragma unroll
        for (int i = 0; i < TW; ++i) acc[i] = bq;

        // XLA conv = cross-correlation: tap k=ky*3+kx hits row h-1+ky, col w-1+kx.
        // Output col i uses window cols i, i+1, i+2.
        #pragma unroll
        for (int kx = 0; kx < 3; ++kx) {
            #pragma unroll
            for (int i = 0; i < TW; ++i) {
                acc[i] = fma4(wk[0 + kx], A[i + kx], acc[i]);
                acc[i] = fma4(wk[3 + kx], B[i + kx], acc[i]);
                acc[i] = fma4(wk[6 + kx], C[i + kx], acc[i]);
            }
        }

        // Write-once output: nontemporal store keeps the 201 MB write stream
        // from evicting input halo lines neighbor blocks re-read via L2/LLC.
        #pragma unroll
        for (int i = 0; i < TW; ++i) {
            f32x4 av;
            av.x = acc[i].x; av.y = acc[i].y; av.z = acc[i].z; av.w = acc[i].w;
            __builtin_nontemporal_store(av,
                (f32x4*)(ob + (long)h * rowstride + (long)i * DIM));
        }

        #pragma unroll
        for (int j = 0; j < 6; ++j) { A[j] = B[j]; B[j] = C[j]; C[j] = D[j]; }
    }
}

extern "C" void kernel_launch(void* const* d_in, const int* in_sizes, int n_in,
                              void* d_out, int out_size, void* d_ws, size_t ws_size,
                              hipStream_t stream) {
    const float* x     = (const float*)d_in[0];
    const float* shift = (const float*)d_in[1];
    const float* sgn   = (const float*)d_in[2];
    const float* bias  = (const float*)d_in[3];
    float* out  = (float*)d_out;
    float* wbuf = (float*)d_ws;        // 9*768 floats
    float* bbuf = wbuf + 9 * DIM;      // 768 floats  (total 30 KB < ws_size)

    wprep_kernel<<<(DIM * 9 + 255) / 256, 256, 0, stream>>>(shift, sgn, bias, wbuf, bbuf);

    dim3 grid(NBX, NBY, BD);           // 16 x 8 x 16 = 2048 blocks
    dwconv_kernel<<<grid, 192, 0, stream>>>(x, wbuf, bbuf, out);
}